// Round 12
// baseline (174.991 us; speedup 1.0000x reference)
//
#include <hip/hip_runtime.h>

#define M_ANT 64
#define POWER_CONSTR 1.0f

typedef float f32x4 __attribute__((ext_vector_type(4)));

// ---------------------------------------------------------------------------
// Kernel 1: per-block partial energies per antenna — HIGH-TLP shape.
// 8192 blocks x 256 threads: each thread does only 8 loads (2 x 4-unrolled
// grid-stride steps) — toward the fill-kernel shape that R11 proved out for
// pass3 (TLP from waves, not per-thread loops). Grid stride is a multiple of
// 256 float4s -> antenna FIXED per thread = (tid>>2)&63. NT loads (R7 win).
// Fixed-order LDS combine (deterministic). No fences/atomics (R10 disaster).
// ---------------------------------------------------------------------------
__global__ __launch_bounds__(256) void energy_partial(
    const f32x4* __restrict__ P4, float* __restrict__ partials, int nvec) {
  const int tid = threadIdx.x;
  const int gtid = blockIdx.x * 256 + tid;
  const int stride = gridDim.x * 256;

  float acc = 0.0f;
  int f = gtid;
  for (; f + 3 * stride < nvec; f += 4 * stride) {
    f32x4 a = __builtin_nontemporal_load(&P4[f]);
    f32x4 b = __builtin_nontemporal_load(&P4[f + stride]);
    f32x4 c = __builtin_nontemporal_load(&P4[f + 2 * stride]);
    f32x4 d = __builtin_nontemporal_load(&P4[f + 3 * stride]);
    acc += a.x * a.x + a.y * a.y + a.z * a.z + a.w * a.w;
    acc += b.x * b.x + b.y * b.y + b.z * b.z + b.w * b.w;
    acc += c.x * c.x + c.y * c.y + c.z * c.z + c.w * c.w;
    acc += d.x * d.x + d.y * d.y + d.z * d.z + d.w * d.w;
  }
  for (; f < nvec; f += stride) {
    f32x4 v = __builtin_nontemporal_load(&P4[f]);
    acc += v.x * v.x + v.y * v.y + v.z * v.z + v.w * v.w;
  }

  __shared__ float part[256];
  part[tid] = acc;
  __syncthreads();
  if (tid < 64) {
    // threads 4a..4a+3 all hold antenna a
    float s = (part[4 * tid] + part[4 * tid + 1]) +
              (part[4 * tid + 2] + part[4 * tid + 3]);
    partials[blockIdx.x * 64 + tid] = s;
  }
}

// ---------------------------------------------------------------------------
// Kernel 2: reduce partials[nblocks][64] -> scale[64].
// 1 block x 1024 threads: thread (j=tid>>6, a=tid&63) sums blocks b===j
// (mod 16), coalesced 256B wave reads. 4-way accumulator MLP to tolerate
// the 4x-larger partials (8192 blocks). Fixed-order -> deterministic.
// ---------------------------------------------------------------------------
__global__ __launch_bounds__(1024) void energy_finalize(
    const float* __restrict__ partials, float* __restrict__ scale, int nblocks) {
  const int tid = threadIdx.x;
  const int a = tid & 63;
  const int j = tid >> 6;  // 0..15
  float s0 = 0.f, s1 = 0.f, s2 = 0.f, s3 = 0.f;
  int b = j;
  for (; b + 48 < nblocks; b += 64) {
    s0 += partials[b * 64 + a];
    s1 += partials[(b + 16) * 64 + a];
    s2 += partials[(b + 32) * 64 + a];
    s3 += partials[(b + 48) * 64 + a];
  }
  for (; b < nblocks; b += 16) s0 += partials[b * 64 + a];
  __shared__ float part[1024];
  part[tid] = (s0 + s1) + (s2 + s3);
  __syncthreads();
  if (tid < 512) part[tid] += part[tid + 512];
  __syncthreads();
  if (tid < 256) part[tid] += part[tid + 256];
  __syncthreads();
  if (tid < 128) part[tid] += part[tid + 128];
  __syncthreads();
  if (tid < 64) {
    const float energy = part[tid] + part[tid + 64];
    scale[tid] = sqrtf(POWER_CONSTR / energy);
  }
}

// ---------------------------------------------------------------------------
// Kernel 3: out = P * scale[antenna] — FLAT fill-kernel shape (R11 win).
// One float4 per thread, 65536 blocks, no loop: pure TLP. Block base is a
// multiple of 256 float4s -> antenna = (tid>>2)&63, staged once in LDS.
// nt load + nt store (R5/R7 A/B wins).
// ---------------------------------------------------------------------------
__global__ __launch_bounds__(256) void apply_scale_flat(
    const f32x4* __restrict__ P4, const float* __restrict__ scale,
    f32x4* __restrict__ O4, int nvec) {
  __shared__ float s_scale[M_ANT];
  if (threadIdx.x < M_ANT) s_scale[threadIdx.x] = scale[threadIdx.x];
  __syncthreads();

  const int f = blockIdx.x * 256 + threadIdx.x;
  if (f < nvec) {
    const float sc = s_scale[(threadIdx.x >> 2) & 63];
    f32x4 v = __builtin_nontemporal_load(&P4[f]);
    v *= sc;
    __builtin_nontemporal_store(v, &O4[f]);
  }
}

extern "C" void kernel_launch(void* const* d_in, const int* in_sizes, int n_in,
                              void* d_out, int out_size, void* d_ws, size_t ws_size,
                              hipStream_t stream) {
  const f32x4* P4 = (const f32x4*)d_in[0];
  f32x4* O4 = (f32x4*)d_out;
  float* ws = (float*)d_ws;

  const int nelem = in_sizes[0];  // B * 2*M*K = 67,108,864
  const int nvec = nelem / 4;     // float4 count

  // Pass-1 grid: 8192 blocks (8 loads/thread), clamped to ws capacity.
  int nblocks1 = 8192;
  const size_t ws_floats = ws_size / sizeof(float);
  if (ws_floats < (size_t)nblocks1 * 64 + 64) {
    size_t cap = ws_floats > 64 ? (ws_floats - 64) / 64 : 1;
    nblocks1 = (int)(cap < 1 ? 1 : cap);
  }
  if (nblocks1 > (nvec + 255) / 256) nblocks1 = (nvec + 255) / 256;

  float* partials = ws;                       // nblocks1 * 64 floats
  float* scale = ws + (size_t)nblocks1 * 64;  // 64 floats

  energy_partial<<<nblocks1, 256, 0, stream>>>(P4, partials, nvec);
  energy_finalize<<<1, 1024, 0, stream>>>(partials, scale, nblocks1);

  // Flat grid: one float4 per thread.
  int nblocks3 = (nvec + 255) / 256;  // 65536 for the full problem
  apply_scale_flat<<<nblocks3, 256, 0, stream>>>(P4, scale, O4, nvec);
}

// Round 13
// 163.831 us; speedup vs baseline: 1.0681x; 1.0681x over previous
//
#include <hip/hip_runtime.h>

#define M_ANT 64
#define POWER_CONSTR 1.0f

typedef float f32x4 __attribute__((ext_vector_type(4)));

// ---------------------------------------------------------------------------
// Kernel 1: per-block partial energies per antenna — R11-exact (best known).
// 2048 blocks x 256 threads grid-stride (8192 blocks WORSE R12; contiguous
// WORSE R9). Antenna fixed per thread = (tid>>2)&63. 4-deep unroll (8-deep
// worse R4). NT loads (R7 win). Fixed-order LDS combine (deterministic).
// No fences/atomics (R10: per-wave device fence = 263 GB/s disaster).
// ---------------------------------------------------------------------------
__global__ __launch_bounds__(256) void energy_partial(
    const f32x4* __restrict__ P4, float* __restrict__ partials, int nvec) {
  const int tid = threadIdx.x;
  const int gtid = blockIdx.x * 256 + tid;
  const int stride = gridDim.x * 256;

  float acc = 0.0f;
  int f = gtid;
  for (; f + 3 * stride < nvec; f += 4 * stride) {
    f32x4 a = __builtin_nontemporal_load(&P4[f]);
    f32x4 b = __builtin_nontemporal_load(&P4[f + stride]);
    f32x4 c = __builtin_nontemporal_load(&P4[f + 2 * stride]);
    f32x4 d = __builtin_nontemporal_load(&P4[f + 3 * stride]);
    acc += a.x * a.x + a.y * a.y + a.z * a.z + a.w * a.w;
    acc += b.x * b.x + b.y * b.y + b.z * b.z + b.w * b.w;
    acc += c.x * c.x + c.y * c.y + c.z * c.z + c.w * c.w;
    acc += d.x * d.x + d.y * d.y + d.z * d.z + d.w * d.w;
  }
  for (; f < nvec; f += stride) {
    f32x4 v = __builtin_nontemporal_load(&P4[f]);
    acc += v.x * v.x + v.y * v.y + v.z * v.z + v.w * v.w;
  }

  __shared__ float part[256];
  part[tid] = acc;
  __syncthreads();
  if (tid < 64) {
    // threads 4a..4a+3 all hold antenna a
    float s = (part[4 * tid] + part[4 * tid + 1]) +
              (part[4 * tid + 2] + part[4 * tid + 3]);
    partials[blockIdx.x * 64 + tid] = s;
  }
}

// ---------------------------------------------------------------------------
// Kernel 2: reduce partials[nblocks][64] -> scale[64]. R11-exact.
// 1 block x 1024 threads: thread (j=tid>>6, a=tid&63) sums blocks b===j (mod 16)
// -> coalesced 256B wave reads, 16-way MLP. Fixed-order LDS tree over j.
// ---------------------------------------------------------------------------
__global__ __launch_bounds__(1024) void energy_finalize(
    const float* __restrict__ partials, float* __restrict__ scale, int nblocks) {
  const int tid = threadIdx.x;
  const int a = tid & 63;
  const int j = tid >> 6;  // 0..15
  float s = 0.0f;
  for (int b = j; b < nblocks; b += 16) s += partials[b * 64 + a];
  __shared__ float part[1024];
  part[tid] = s;
  __syncthreads();
  if (tid < 512) part[tid] += part[tid + 512];
  __syncthreads();
  if (tid < 256) part[tid] += part[tid + 256];
  __syncthreads();
  if (tid < 128) part[tid] += part[tid + 128];
  __syncthreads();
  if (tid < 64) {
    const float energy = part[tid] + part[tid + 64];
    scale[tid] = sqrtf(POWER_CONSTR / energy);
  }
}

// ---------------------------------------------------------------------------
// Kernel 3: out = P * scale[antenna] — FLAT shape (R11 win), NO LDS/barrier.
// One float4 per thread, no loop: pure TLP. Each thread reads its single
// scale value directly from global (256B table, L2-hit broadcast after the
// first blocks) — removes the per-block LDS stage + __syncthreads() that sat
// in front of every block's only load/store. nt load + nt store for the
// streams (R5/R7 wins); scale read stays cached (reused by all blocks).
// ---------------------------------------------------------------------------
__global__ __launch_bounds__(256) void apply_scale_flat(
    const f32x4* __restrict__ P4, const float* __restrict__ scale,
    f32x4* __restrict__ O4, int nvec) {
  const int f = blockIdx.x * 256 + threadIdx.x;
  if (f < nvec) {
    const float sc = scale[(threadIdx.x >> 2) & 63];
    f32x4 v = __builtin_nontemporal_load(&P4[f]);
    v *= sc;
    __builtin_nontemporal_store(v, &O4[f]);
  }
}

extern "C" void kernel_launch(void* const* d_in, const int* in_sizes, int n_in,
                              void* d_out, int out_size, void* d_ws, size_t ws_size,
                              hipStream_t stream) {
  const f32x4* P4 = (const f32x4*)d_in[0];
  f32x4* O4 = (f32x4*)d_out;
  float* ws = (float*)d_ws;

  const int nelem = in_sizes[0];  // B * 2*M*K = 67,108,864
  const int nvec = nelem / 4;     // float4 count

  // Pass-1 grid: 2048 blocks (8 blocks/CU), clamped to ws capacity.
  int nblocks1 = 2048;
  const size_t ws_floats = ws_size / sizeof(float);
  if (ws_floats < (size_t)nblocks1 * 64 + 64) {
    size_t cap = ws_floats > 64 ? (ws_floats - 64) / 64 : 1;
    nblocks1 = (int)(cap < 1 ? 1 : cap);
  }
  if (nblocks1 > (nvec + 255) / 256) nblocks1 = (nvec + 255) / 256;

  float* partials = ws;                       // nblocks1 * 64 floats
  float* scale = ws + (size_t)nblocks1 * 64;  // 64 floats

  energy_partial<<<nblocks1, 256, 0, stream>>>(P4, partials, nvec);
  energy_finalize<<<1, 1024, 0, stream>>>(partials, scale, nblocks1);

  // Flat grid: one float4 per thread.
  int nblocks3 = (nvec + 255) / 256;  // 65536 for the full problem
  apply_scale_flat<<<nblocks3, 256, 0, stream>>>(P4, scale, O4, nvec);
}